// Round 4
// baseline (164.848 us; speedup 1.0000x reference)
//
#include <hip/hip_runtime.h>
#include <stdint.h>

// B=8, T=64, N=128, FIN=64, D=64, LAG=8.  Rows (b,t,n): 65536 x 64.

typedef __bf16 bf16x8 __attribute__((ext_vector_type(8)));
typedef float f32x4 __attribute__((ext_vector_type(4)));

#define MFMA16(a, b, c) __builtin_amdgcn_mfma_f32_16x16x32_bf16((a), (b), (c), 0, 0, 0)

__device__ __forceinline__ unsigned short f2bf(float f) {
    union { float f; unsigned u; } v; v.f = f;
    unsigned r = v.u + 0x7FFFu + ((v.u >> 16) & 1u);
    return (unsigned short)(r >> 16);
}
__device__ __forceinline__ unsigned cvtpk(float lo, float hi) {
    unsigned r;
    asm("v_cvt_pk_bf16_f32 %0, %1, %2" : "=v"(r) : "v"(lo), "v"(hi));
    return r;
}
__device__ __forceinline__ f32x4 fzero4() {
    f32x4 z; z[0] = 0.f; z[1] = 0.f; z[2] = 0.f; z[3] = 0.f; return z;
}

// ---------------------------------------------------------------------------
// Kernel 0: one-time weight transpose + bf16 convert.
// Block b: 0->WqT, 1->WkT, 2->WvT (all [64 d][64 f]), 3->WoT [64 dout][128 c].
// ---------------------------------------------------------------------------
__global__ __launch_bounds__(256) void prep_kernel(
    const float* __restrict__ Wq, const float* __restrict__ Wk,
    const float* __restrict__ Wv, const float* __restrict__ Wo,
    unsigned short* __restrict__ WqT, unsigned short* __restrict__ WkT,
    unsigned short* __restrict__ WvT, unsigned short* __restrict__ WoT)
{
    __shared__ float lds[128][65];
    const int b = blockIdx.x, tid = threadIdx.x;
    const float* src = (b == 0) ? Wq : (b == 1) ? Wk : (b == 2) ? Wv : Wo;
    unsigned short* dst = (b == 0) ? WqT : (b == 1) ? WkT : (b == 2) ? WvT : WoT;
    const int n = (b == 3) ? 8192 : 4096;      // src R x 64, R = 64 or 128
    for (int i = tid; i < n; i += 256) lds[i >> 6][i & 63] = src[i];
    __syncthreads();
    if (b == 3) {
        for (int i = tid; i < 8192; i += 256) { int d = i >> 7, r = i & 127; dst[i] = f2bf(lds[r][d]); }
    } else {
        for (int i = tid; i < 4096; i += 256) { int d = i >> 6, r = i & 63;  dst[i] = f2bf(lds[r][d]); }
    }
}

// ---------------------------------------------------------------------------
// Kernel 1: QKV projection via MFMA. No LDS, no barriers — weights come
// pre-transposed in bf16 from prep_kernel (L2-resident, same addresses for
// every block). Grid 1024 x 256 (4 waves x 16 rows).
// Q,K stored row-major [row][64]; V stored transposed per (b,t): [64 d][128 n].
// ---------------------------------------------------------------------------
__global__ __launch_bounds__(256) void qkv_kernel(
    const float* __restrict__ X,
    const unsigned short* __restrict__ WqT, const unsigned short* __restrict__ WkT,
    const unsigned short* __restrict__ WvT,
    const float* __restrict__ bq, const float* __restrict__ bk, const float* __restrict__ bv,
    unsigned short* __restrict__ Qo, unsigned short* __restrict__ Ko,
    unsigned short* __restrict__ Vt)
{
    const int tid = threadIdx.x, lane = tid & 63, w = tid >> 6;
    const int cl = lane & 15, g = lane >> 4;
    const size_t row0 = (size_t)blockIdx.x * 64 + w * 16;
    const int bt = (int)(row0 >> 7);
    const int nb = (int)(row0 & 127);

    // X fragments: lane holds X[row0+cl][kk*32+g*8 .. +7] as bf16
    bf16x8 xf[2];
    {
        const float* xp = X + (row0 + cl) * 64;
#pragma unroll
        for (int kk = 0; kk < 2; ++kk) {
            float4 a = *(const float4*)(xp + kk * 32 + g * 8);
            float4 b = *(const float4*)(xp + kk * 32 + g * 8 + 4);
            unsigned u[4];
            u[0] = cvtpk(a.x, a.y); u[1] = cvtpk(a.z, a.w);
            u[2] = cvtpk(b.x, b.y); u[3] = cvtpk(b.z, b.w);
            xf[kk] = *(bf16x8*)u;
        }
    }

    f32x4 accq[4], acck[4], accv[4];
#pragma unroll
    for (int i = 0; i < 4; ++i) { accq[i] = fzero4(); acck[i] = fzero4(); accv[i] = fzero4(); }

#pragma unroll
    for (int kk = 0; kk < 2; ++kk) {
        const int wo = kk * 32 + g * 8;
#pragma unroll
        for (int dt = 0; dt < 4; ++dt) {
            const int rw = (dt * 16 + cl) * 64 + wo;
            bf16x8 wqf = *(const bf16x8*)(WqT + rw);
            bf16x8 wkf = *(const bf16x8*)(WkT + rw);
            bf16x8 wvf = *(const bf16x8*)(WvT + rw);
            accq[dt] = MFMA16(wqf, xf[kk], accq[dt]);   // D[dq][n]
            acck[dt] = MFMA16(wkf, xf[kk], acck[dt]);   // D[dk][n]
            accv[dt] = MFMA16(xf[kk], wvf, accv[dt]);   // D[n][dv]
        }
    }

#pragma unroll
    for (int dt = 0; dt < 4; ++dt) {
        // Q,K: lane holds col n=row0+cl, rows c = dt*16+g*4+r -> 8B row-major stores
        float4 bq4 = *(const float4*)(bq + dt * 16 + g * 4);
        float q0 = fmaxf(accq[dt][0] + bq4.x, 0.f);
        float q1 = fmaxf(accq[dt][1] + bq4.y, 0.f);
        float q2 = fmaxf(accq[dt][2] + bq4.z, 0.f);
        float q3 = fmaxf(accq[dt][3] + bq4.w, 0.f);
        uint2 qp; qp.x = cvtpk(q0, q1); qp.y = cvtpk(q2, q3);
        *(uint2*)(Qo + (row0 + cl) * 64 + dt * 16 + g * 4) = qp;

        float4 bk4 = *(const float4*)(bk + dt * 16 + g * 4);
        float k0 = fmaxf(acck[dt][0] + bk4.x, 0.f);
        float k1 = fmaxf(acck[dt][1] + bk4.y, 0.f);
        float k2 = fmaxf(acck[dt][2] + bk4.z, 0.f);
        float k3 = fmaxf(acck[dt][3] + bk4.w, 0.f);
        uint2 kp; kp.x = cvtpk(k0, k1); kp.y = cvtpk(k2, k3);
        *(uint2*)(Ko + (row0 + cl) * 64 + dt * 16 + g * 4) = kp;

        // V: lane holds col d=dt*16+cl, rows n = nb+g*4+r -> 8B stores of V^T
        float bvv = bv[dt * 16 + cl];
        float v0 = fmaxf(accv[dt][0] + bvv, 0.f);
        float v1 = fmaxf(accv[dt][1] + bvv, 0.f);
        float v2 = fmaxf(accv[dt][2] + bvv, 0.f);
        float v3 = fmaxf(accv[dt][3] + bvv, 0.f);
        uint2 vp; vp.x = cvtpk(v0, v1); vp.y = cvtpk(v2, v3);
        *(uint2*)(Vt + (size_t)bt * 8192 + (dt * 16 + cl) * 128 + nb + g * 4) = vp;
    }
}

// ---------------------------------------------------------------------------
// Kernel 2: lag attention + output projection. Grid 512 x 512 threads (8 waves
// x 16 queries). Swapped-operand QK^T, no max-tracking softmax, register
// prefetch of next chunk, XCD-chunked block swizzle.
// __launch_bounds__(512,2): cap 256 VGPR — (512,4) forced a 122MB scratch spill.
// ---------------------------------------------------------------------------
__global__ __launch_bounds__(512, 2) void attn_kernel(
    const unsigned short* __restrict__ Qg,
    const unsigned short* __restrict__ Kg,
    const unsigned short* __restrict__ Vt,
    const unsigned short* __restrict__ WoT,
    const float* __restrict__ bo,
    float* __restrict__ Out)
{
    __shared__ __align__(16) unsigned char ldsK[16384];  // K [128key][64d]; later h(agg) [128q][64c]
    __shared__ __align__(16) unsigned char ldsV[16384];  // V^T [64d][128key]; later Wo^T [64][128]
    __shared__ __align__(16) unsigned char ldsP[32768];  // P [128q][128key] bf16 (per-wave regions)
    __shared__ float lsumBuf[128];

    const int tid = threadIdx.x;
    const int lane = tid & 63, wv = tid >> 6;
    const int cl = lane & 15, g = lane >> 4;
    const int bid = blockIdx.x;
    const int bt = (bid & 7) * 64 + (bid >> 3);   // XCD-chunked swizzle (512 % 8 == 0)
    const int t = bt & 63;
    const int wq0 = wv * 16;

    // Q fragments (B-operand of S^T; A-operand of out-proj)
    bf16x8 qf[2];
    {
        const unsigned short* qp = Qg + ((size_t)bt * 128 + wq0 + cl) * 64;
        qf[0] = *(const bf16x8*)(qp + g * 8);
        qf[1] = *(const bf16x8*)(qp + 32 + g * 8);
    }

    f32x4 o[4];
#pragma unroll
    for (int ni = 0; ni < 4; ++ni) o[ni] = fzero4();
    float lsum = 0.f;

    const int lg0 = (t < 7) ? (7 - t) : 0;

    uint4 kreg[2], vreg[2];
    {
        const uint4* kp = (const uint4*)(Kg + (size_t)(bt - 7 + lg0) * 8192);
        const uint4* vp = (const uint4*)(Vt + (size_t)(bt - 7 + lg0) * 8192);
        kreg[0] = kp[tid]; kreg[1] = kp[tid + 512];
        vreg[0] = vp[tid]; vreg[1] = vp[tid + 512];
    }

    for (int lg = lg0; lg < 8; ++lg) {
        __syncthreads();   // previous chunk fully consumed
        {   // staged regs -> LDS (swizzled, vector b128 writes)
#pragma unroll
            for (int j = 0; j < 2; ++j) {
                int i = tid + j * 512;
                int key = i >> 3, d0 = (i & 7) * 8;
                *(uint4*)(ldsK + ((key * 128 + d0 * 2) ^ ((key & 7) << 4))) = kreg[j];
                int d = i >> 4, n0 = (i & 15) * 8;
                *(uint4*)(ldsV + ((d * 256 + n0 * 2) ^ ((d & 7) << 4))) = vreg[j];
            }
        }
        if (lg < 7) {   // prefetch next chunk (in flight across the compute below)
            const uint4* kp = (const uint4*)(Kg + (size_t)(bt - 6 + lg) * 8192);
            const uint4* vp = (const uint4*)(Vt + (size_t)(bt - 6 + lg) * 8192);
            kreg[0] = kp[tid]; kreg[1] = kp[tid + 512];
            vreg[0] = vp[tid]; vreg[1] = vp[tid + 512];
        }
        __syncthreads();   // chunk staged

        // S^T = K Q^T : D[key][q], lane: q = wq0+cl (col), keys ki*16+g*4+r (rows)
        f32x4 s[8];
#pragma unroll
        for (int ki = 0; ki < 8; ++ki) s[ki] = fzero4();
#pragma unroll
        for (int ki = 0; ki < 8; ++ki) {
            int key = ki * 16 + cl;
#pragma unroll
            for (int kk = 0; kk < 2; ++kk) {
                bf16x8 kf = *(const bf16x8*)(ldsK + ((key * 128 + (kk * 32 + g * 8) * 2) ^ ((key & 7) << 4)));
                s[ki] = MFMA16(kf, qf[kk], s[ki]);
            }
        }

        // p = exp(s/8); accumulate per-lane partial row-sum; pack 4 keys -> b64 P write
        const int q = wq0 + cl;
#pragma unroll
        for (int ki = 0; ki < 8; ++ki) {
            float p0 = __expf(s[ki][0] * 0.125f);
            float p1 = __expf(s[ki][1] * 0.125f);
            float p2 = __expf(s[ki][2] * 0.125f);
            float p3 = __expf(s[ki][3] * 0.125f);
            lsum += (p0 + p1) + (p2 + p3);
            uint2 pk; pk.x = cvtpk(p0, p1); pk.y = cvtpk(p2, p3);
            *(uint2*)(ldsP + ((q * 256 + (ki * 16 + g * 4) * 2) ^ ((q & 7) << 4))) = pk;
        }

        // O += P V  (A = own-wave P rows, B = V^T)
#pragma unroll
        for (int kk2 = 0; kk2 < 4; ++kk2) {
            bf16x8 pf = *(const bf16x8*)(ldsP + ((q * 256 + (kk2 * 32 + g * 8) * 2) ^ ((q & 7) << 4)));
#pragma unroll
            for (int ni = 0; ni < 4; ++ni) {
                int d = ni * 16 + cl;
                bf16x8 vf = *(const bf16x8*)(ldsV + ((d * 256 + (kk2 * 32 + g * 8) * 2) ^ ((d & 7) << 4)));
                o[ni] = MFMA16(pf, vf, o[ni]);
            }
        }
    }

    // finalize row sums: reduce over the 4 g-lanes holding the same q
    float ls = lsum;
    ls += __shfl_xor(ls, 16, 64);
    ls += __shfl_xor(ls, 32, 64);
    if (t < 7) ls += 128.0f * (float)(7 - t);   // padded lags: exp(0)=1 each
    if (g == 0) lsumBuf[wq0 + cl] = ls;
    __syncthreads();   // lsum visible; all waves done with ldsK/ldsV

    // agg = O/lsum -> ldsK as h rows [128 q][64 c] bf16 (swizzled)
    float inv[4];
#pragma unroll
    for (int r = 0; r < 4; ++r) inv[r] = 1.0f / lsumBuf[wq0 + g * 4 + r];
#pragma unroll
    for (int ni = 0; ni < 4; ++ni)
#pragma unroll
        for (int r = 0; r < 4; ++r) {
            int qq = wq0 + g * 4 + r;
            int d = ni * 16 + cl;
            *(unsigned short*)(ldsK + ((qq * 128 + d * 2) ^ ((qq & 7) << 4))) =
                f2bf(o[ni][r] * inv[r]);
        }

    // stage Wo^T [64 dout][128 c] bf16 into ldsV (vector copies, already bf16)
    {
        const uint4* wo4 = (const uint4*)WoT;
#pragma unroll
        for (int j = 0; j < 2; ++j) {
            int i = tid + j * 512;
            int d = i >> 4, c0 = (i & 15) * 8;
            *(uint4*)(ldsV + ((d * 256 + c0 * 2) ^ ((d & 7) << 4))) = wo4[i];
        }
    }
    __syncthreads();

    // out = relu([Q | agg] @ Wo + bo)
    f32x4 h2[4];
#pragma unroll
    for (int ni = 0; ni < 4; ++ni) h2[ni] = fzero4();
#pragma unroll
    for (int kk = 0; kk < 4; ++kk) {
        bf16x8 ha;
        if (kk < 2) {
            ha = qf[kk];
        } else {
            int qq = wq0 + cl;
            ha = *(const bf16x8*)(ldsK + ((qq * 128 + ((kk - 2) * 32 + g * 8) * 2) ^ ((qq & 7) << 4)));
        }
#pragma unroll
        for (int ni = 0; ni < 4; ++ni) {
            int dd = ni * 16 + cl;
            bf16x8 wb = *(const bf16x8*)(ldsV + ((dd * 256 + (kk * 32 + g * 8) * 2) ^ ((dd & 7) << 4)));
            h2[ni] = MFMA16(ha, wb, h2[ni]);
        }
    }
#pragma unroll
    for (int ni = 0; ni < 4; ++ni) {
        float b = bo[ni * 16 + cl];
#pragma unroll
        for (int r = 0; r < 4; ++r) {
            float v = h2[ni][r] + b;
            v = v > 0.f ? v : 0.f;
            Out[((size_t)bt * 128 + wq0 + g * 4 + r) * 64 + ni * 16 + cl] = v;
        }
    }
}

// ---------------------------------------------------------------------------
extern "C" void kernel_launch(void* const* d_in, const int* in_sizes, int n_in,
                              void* d_out, int out_size, void* d_ws, size_t ws_size,
                              hipStream_t stream) {
    const float* X  = (const float*)d_in[0];
    const float* Wq = (const float*)d_in[1];
    const float* bq = (const float*)d_in[2];
    const float* Wk = (const float*)d_in[3];
    const float* bk = (const float*)d_in[4];
    const float* Wv = (const float*)d_in[5];
    const float* bv = (const float*)d_in[6];
    const float* Wo = (const float*)d_in[7];
    const float* bo = (const float*)d_in[8];
    float* Out = (float*)d_out;

    unsigned short* Qw = (unsigned short*)d_ws;            // 3 x 8 MB bf16
    unsigned short* Kw = Qw + (size_t)65536 * 64;
    unsigned short* Vw = Kw + (size_t)65536 * 64;          // V^T per (b,t): [64][128]
    unsigned short* Wt  = Vw + (size_t)65536 * 64;         // +40 KB weight tables
    unsigned short* WqT = Wt;
    unsigned short* WkT = Wt + 4096;
    unsigned short* WvT = Wt + 8192;
    unsigned short* WoT = Wt + 12288;

    hipLaunchKernelGGL(prep_kernel, dim3(4), dim3(256), 0, stream,
                       Wq, Wk, Wv, Wo, WqT, WkT, WvT, WoT);
    hipLaunchKernelGGL(qkv_kernel, dim3(1024), dim3(256), 0, stream,
                       X, WqT, WkT, WvT, bq, bk, bv, Qw, Kw, Vw);
    hipLaunchKernelGGL(attn_kernel, dim3(512), dim3(512), 0, stream,
                       Qw, Kw, Vw, WoT, bo, Out);
}

// Round 5
// 137.525 us; speedup vs baseline: 1.1987x; 1.1987x over previous
//
#include <hip/hip_runtime.h>
#include <stdint.h>

// B=8, T=64, N=128, FIN=64, D=64, LAG=8.  Rows (b,t,n): 65536 x 64.
// Single fused kernel: per (b,t) block regenerates K,V for each lag chunk
// from X via MFMA (A-frag of K-gen == B-frag of V-gen == own X rows in regs),
// eliminating the QKV pre-pass and its 24MB HBM round trip.

typedef __bf16 bf16x8 __attribute__((ext_vector_type(8)));
typedef float f32x4 __attribute__((ext_vector_type(4)));

#define MFMA16(a, b, c) __builtin_amdgcn_mfma_f32_16x16x32_bf16((a), (b), (c), 0, 0, 0)

__device__ __forceinline__ unsigned short f2bf(float f) {
    union { float f; unsigned u; } v; v.f = f;
    unsigned r = v.u + 0x7FFFu + ((v.u >> 16) & 1u);
    return (unsigned short)(r >> 16);
}
__device__ __forceinline__ unsigned cvtpk(float lo, float hi) {
    unsigned r;
    asm("v_cvt_pk_bf16_f32 %0, %1, %2" : "=v"(r) : "v"(lo), "v"(hi));
    return r;
}
__device__ __forceinline__ f32x4 fzero4() {
    f32x4 z; z[0] = 0.f; z[1] = 0.f; z[2] = 0.f; z[3] = 0.f; return z;
}

// ---------------------------------------------------------------------------
// Kernel 0: one-time weight transpose + bf16 convert.
// Block b: 0->WqT, 1->WkT, 2->WvT (all [64 d][64 f]), 3->WoT [64 dout][128 c].
// ---------------------------------------------------------------------------
__global__ __launch_bounds__(256) void prep_kernel(
    const float* __restrict__ Wq, const float* __restrict__ Wk,
    const float* __restrict__ Wv, const float* __restrict__ Wo,
    unsigned short* __restrict__ WqT, unsigned short* __restrict__ WkT,
    unsigned short* __restrict__ WvT, unsigned short* __restrict__ WoT)
{
    __shared__ float lds[128][65];
    const int b = blockIdx.x, tid = threadIdx.x;
    const float* src = (b == 0) ? Wq : (b == 1) ? Wk : (b == 2) ? Wv : Wo;
    unsigned short* dst = (b == 0) ? WqT : (b == 1) ? WkT : (b == 2) ? WvT : WoT;
    const int n = (b == 3) ? 8192 : 4096;      // src R x 64, R = 64 or 128
    for (int i = tid; i < n; i += 256) lds[i >> 6][i & 63] = src[i];
    __syncthreads();
    if (b == 3) {
        for (int i = tid; i < 8192; i += 256) { int d = i >> 7, r = i & 127; dst[i] = f2bf(lds[r][d]); }
    } else {
        for (int i = tid; i < 4096; i += 256) { int d = i >> 6, r = i & 63;  dst[i] = f2bf(lds[r][d]); }
    }
}

// ---------------------------------------------------------------------------
// Fused kernel: one block per (b,t), 8 waves x 16 queries, 512 threads.
// Per lag chunk: regenerate K,V from X (16 MFMA) -> swizzled LDS, then
// QK^T -> exp -> PV exactly as before. Q generated at first chunk (st==t)
// into the P region (safe: P writes only start after the KV-ready barrier).
// LDS = 64KB exactly -> 2 blocks/CU.
// ---------------------------------------------------------------------------
__global__ __launch_bounds__(512, 2) void fused_kernel(
    const float* __restrict__ X,
    const unsigned short* __restrict__ WqT, const unsigned short* __restrict__ WkT,
    const unsigned short* __restrict__ WvT, const unsigned short* __restrict__ WoT,
    const float* __restrict__ bq, const float* __restrict__ bk,
    const float* __restrict__ bv, const float* __restrict__ bo,
    float* __restrict__ Out)
{
    __shared__ __align__(16) unsigned char ldsK[16384];  // K [128key][64d] swz; later agg h [128q][64c]
    __shared__ __align__(16) unsigned char ldsVt[16384]; // V^T [64d][128key] swz; later Wo^T [64][128]
    __shared__ __align__(16) unsigned char ldsP[32768];  // P [128q][128key] swz; first chunk: Q [128q][64d]

    const int tid = threadIdx.x;
    const int lane = tid & 63, wvid = tid >> 6;
    const int cl = lane & 15, g = lane >> 4;
    const int bid = blockIdx.x;
    const int bt = (bid & 7) * 64 + (bid >> 3);   // XCD swizzle: batch b -> XCD b (L2 locality)
    const int t = bt & 63;
    const int wq0 = wvid * 16;
    const int q = wq0 + cl;                       // this lane's query column

    // ---- hoisted weight fragments (L2-hot, same addr for all blocks) ----
    bf16x8 wkF[4][2], wvF[4][2];
#pragma unroll
    for (int dt = 0; dt < 4; ++dt)
#pragma unroll
        for (int kk = 0; kk < 2; ++kk) {
            const int rw = (dt * 16 + cl) * 64 + kk * 32 + g * 8;
            wkF[dt][kk] = *(const bf16x8*)(WkT + rw);
            wvF[dt][kk] = *(const bf16x8*)(WvT + rw);
        }
    float4 bk4[4];
    float bvs[4];
#pragma unroll
    for (int dt = 0; dt < 4; ++dt) {
        bk4[dt] = *(const float4*)(bk + dt * 16 + g * 4);
        bvs[dt] = bv[dt * 16 + cl];
    }

    f32x4 o[4];
#pragma unroll
    for (int ni = 0; ni < 4; ++ni) o[ni] = fzero4();
    float lsum = 0.f;
    bf16x8 qf[2];

    const int lo = (t < 7) ? 0 : (t - 7);

    // X rows for this wave (own 16 rows of chunk st): registers only.
    float4 xr0, xr1, xr2, xr3;
    {
        const float* xp = X + (((size_t)bt) * 128 + wq0 + cl) * 64;   // st = t
        xr0 = *(const float4*)(xp + g * 8);
        xr1 = *(const float4*)(xp + g * 8 + 4);
        xr2 = *(const float4*)(xp + 32 + g * 8);
        xr3 = *(const float4*)(xp + 32 + g * 8 + 4);
    }

    for (int st = t; st >= lo; --st) {
        __syncthreads();   // previous chunk fully consumed (K/V overwrite safe)

        // xf from prefetched registers
        bf16x8 xf[2];
        {
            unsigned u[4];
            u[0] = cvtpk(xr0.x, xr0.y); u[1] = cvtpk(xr0.z, xr0.w);
            u[2] = cvtpk(xr1.x, xr1.y); u[3] = cvtpk(xr1.z, xr1.w);
            xf[0] = *(bf16x8*)u;
            u[0] = cvtpk(xr2.x, xr2.y); u[1] = cvtpk(xr2.z, xr2.w);
            u[2] = cvtpk(xr3.x, xr3.y); u[3] = cvtpk(xr3.z, xr3.w);
            xf[1] = *(bf16x8*)u;
        }
        if (st > lo) {   // prefetch next chunk's X rows (in flight across compute)
            const float* xp = X + (((size_t)bt - (t - st) - 1) * 128 + wq0 + cl) * 64;
            xr0 = *(const float4*)(xp + g * 8);
            xr1 = *(const float4*)(xp + g * 8 + 4);
            xr2 = *(const float4*)(xp + 32 + g * 8);
            xr3 = *(const float4*)(xp + 32 + g * 8 + 4);
        }

        // ---- generate K chunk: D[d][key] = mfma(WkT-frag, xf) ----
        // ---- generate V chunk: D[key][d] = mfma(xf, WvT-frag) ----
#pragma unroll
        for (int dt = 0; dt < 4; ++dt) {
            f32x4 kacc = fzero4(), vacc = fzero4();
            kacc = MFMA16(wkF[dt][0], xf[0], kacc);
            kacc = MFMA16(wkF[dt][1], xf[1], kacc);
            vacc = MFMA16(xf[0], wvF[dt][0], vacc);
            vacc = MFMA16(xf[1], wvF[dt][1], vacc);
            // K: lane col key=wq0+cl, rows d=dt*16+g*4+r -> K_lds[key][d] (4 consec d)
            {
                const int key = wq0 + cl;
                float k0 = fmaxf(kacc[0] + bk4[dt].x, 0.f);
                float k1 = fmaxf(kacc[1] + bk4[dt].y, 0.f);
                float k2 = fmaxf(kacc[2] + bk4[dt].z, 0.f);
                float k3 = fmaxf(kacc[3] + bk4[dt].w, 0.f);
                uint2 kp; kp.x = cvtpk(k0, k1); kp.y = cvtpk(k2, k3);
                *(uint2*)(ldsK + ((key * 128 + (dt * 16 + g * 4) * 2) ^ ((key & 7) << 4))) = kp;
            }
            // V: lane col d=dt*16+cl, rows key=wq0+g*4+r -> Vt_lds[d][key] (4 consec key)
            {
                const int d = dt * 16 + cl;
                float v0 = fmaxf(vacc[0] + bvs[dt], 0.f);
                float v1 = fmaxf(vacc[1] + bvs[dt], 0.f);
                float v2 = fmaxf(vacc[2] + bvs[dt], 0.f);
                float v3 = fmaxf(vacc[3] + bvs[dt], 0.f);
                uint2 vp; vp.x = cvtpk(v0, v1); vp.y = cvtpk(v2, v3);
                *(uint2*)(ldsVt + ((d * 256 + (wq0 + g * 4) * 2) ^ ((d & 7) << 4))) = vp;
            }
        }

        if (st == t) {
            // ---- generate Q (own rows) into ldsP-as-Q, read back qf B-frags ----
#pragma unroll
            for (int dt = 0; dt < 4; ++dt) {
                const int rw = (dt * 16 + cl) * 64;
                bf16x8 wq0f = *(const bf16x8*)(WqT + rw + g * 8);
                bf16x8 wq1f = *(const bf16x8*)(WqT + rw + 32 + g * 8);
                f32x4 qacc = fzero4();
                qacc = MFMA16(wq0f, xf[0], qacc);
                qacc = MFMA16(wq1f, xf[1], qacc);
                float4 bq4 = *(const float4*)(bq + dt * 16 + g * 4);
                float q0 = fmaxf(qacc[0] + bq4.x, 0.f);
                float q1 = fmaxf(qacc[1] + bq4.y, 0.f);
                float q2 = fmaxf(qacc[2] + bq4.z, 0.f);
                float q3 = fmaxf(qacc[3] + bq4.w, 0.f);
                uint2 qp; qp.x = cvtpk(q0, q1); qp.y = cvtpk(q2, q3);
                *(uint2*)(ldsP + ((q * 128 + (dt * 16 + g * 4) * 2) ^ ((q & 7) << 4))) = qp;
            }
            qf[0] = *(const bf16x8*)(ldsP + ((q * 128 + (g * 8) * 2) ^ ((q & 7) << 4)));
            qf[1] = *(const bf16x8*)(ldsP + ((q * 128 + (32 + g * 8) * 2) ^ ((q & 7) << 4)));
        }
        __syncthreads();   // K/V (and Q reads) ready

        // ---- S^T = K Q^T : D[key][q] ----
        f32x4 s[8];
#pragma unroll
        for (int ki = 0; ki < 8; ++ki) s[ki] = fzero4();
#pragma unroll
        for (int ki = 0; ki < 8; ++ki) {
            const int key = ki * 16 + cl;
#pragma unroll
            for (int kk = 0; kk < 2; ++kk) {
                bf16x8 kf = *(const bf16x8*)(ldsK + ((key * 128 + (kk * 32 + g * 8) * 2) ^ ((key & 7) << 4)));
                s[ki] = MFMA16(kf, qf[kk], s[ki]);
            }
        }

        // ---- p = exp(s/8); per-lane partial row sum; P -> LDS (b64 packed) ----
#pragma unroll
        for (int ki = 0; ki < 8; ++ki) {
            float p0 = __expf(s[ki][0] * 0.125f);
            float p1 = __expf(s[ki][1] * 0.125f);
            float p2 = __expf(s[ki][2] * 0.125f);
            float p3 = __expf(s[ki][3] * 0.125f);
            lsum += (p0 + p1) + (p2 + p3);
            uint2 pk; pk.x = cvtpk(p0, p1); pk.y = cvtpk(p2, p3);
            *(uint2*)(ldsP + ((q * 256 + (ki * 16 + g * 4) * 2) ^ ((q & 7) << 4))) = pk;
        }

        // ---- O += P V ----
#pragma unroll
        for (int kk2 = 0; kk2 < 4; ++kk2) {
            bf16x8 pf = *(const bf16x8*)(ldsP + ((q * 256 + (kk2 * 32 + g * 8) * 2) ^ ((q & 7) << 4)));
#pragma unroll
            for (int ni = 0; ni < 4; ++ni) {
                const int d = ni * 16 + cl;
                bf16x8 vf = *(const bf16x8*)(ldsVt + ((d * 256 + (kk2 * 32 + g * 8) * 2) ^ ((d & 7) << 4)));
                o[ni] = MFMA16(pf, vf, o[ni]);
            }
        }
    }

    // ---- row sums (pure shuffles, no LDS) ----
    float ls = lsum;
    ls += __shfl_xor(ls, 16, 64);
    ls += __shfl_xor(ls, 32, 64);
    if (t < 7) ls += 128.0f * (float)(7 - t);   // padded lags contribute exp(0)=1 each
    float inv[4];
#pragma unroll
    for (int r = 0; r < 4; ++r) inv[r] = 1.0f / __shfl(ls, g * 4 + r, 64);

    __syncthreads();   // all waves done reading K/V/P of last chunk

    // agg = O/lsum -> ldsK as h rows [128 q][64 c] bf16 (swizzled)
#pragma unroll
    for (int ni = 0; ni < 4; ++ni)
#pragma unroll
        for (int r = 0; r < 4; ++r) {
            const int qq = wq0 + g * 4 + r;
            const int d = ni * 16 + cl;
            *(unsigned short*)(ldsK + ((qq * 128 + d * 2) ^ ((qq & 7) << 4))) =
                f2bf(o[ni][r] * inv[r]);
        }

    // stage Wo^T [64 dout][128 c] bf16 into ldsVt (vector copies)
    {
        const uint4* wo4 = (const uint4*)WoT;
#pragma unroll
        for (int j = 0; j < 2; ++j) {
            const int i = tid + j * 512;
            const int d = i >> 4, c0 = (i & 15) * 8;
            *(uint4*)(ldsVt + ((d * 256 + c0 * 2) ^ ((d & 7) << 4))) = wo4[i];
        }
    }
    __syncthreads();

    // out = relu([Q | agg] @ Wo + bo)
    f32x4 h2[4];
#pragma unroll
    for (int ni = 0; ni < 4; ++ni) h2[ni] = fzero4();
#pragma unroll
    for (int kk = 0; kk < 4; ++kk) {
        bf16x8 ha;
        if (kk < 2) {
            ha = qf[kk];
        } else {
            ha = *(const bf16x8*)(ldsK + ((q * 128 + ((kk - 2) * 32 + g * 8) * 2) ^ ((q & 7) << 4)));
        }
#pragma unroll
        for (int ni = 0; ni < 4; ++ni) {
            const int dd = ni * 16 + cl;
            bf16x8 wb = *(const bf16x8*)(ldsVt + ((dd * 256 + (kk * 32 + g * 8) * 2) ^ ((dd & 7) << 4)));
            h2[ni] = MFMA16(ha, wb, h2[ni]);
        }
    }
#pragma unroll
    for (int ni = 0; ni < 4; ++ni) {
        const float b = bo[ni * 16 + cl];
#pragma unroll
        for (int r = 0; r < 4; ++r) {
            float v = h2[ni][r] + b;
            v = v > 0.f ? v : 0.f;
            Out[((size_t)bt * 128 + wq0 + g * 4 + r) * 64 + ni * 16 + cl] = v;
        }
    }
}

// ---------------------------------------------------------------------------
extern "C" void kernel_launch(void* const* d_in, const int* in_sizes, int n_in,
                              void* d_out, int out_size, void* d_ws, size_t ws_size,
                              hipStream_t stream) {
    const float* X  = (const float*)d_in[0];
    const float* Wq = (const float*)d_in[1];
    const float* bq = (const float*)d_in[2];
    const float* Wk = (const float*)d_in[3];
    const float* bk = (const float*)d_in[4];
    const float* Wv = (const float*)d_in[5];
    const float* bv = (const float*)d_in[6];
    const float* Wo = (const float*)d_in[7];
    const float* bo = (const float*)d_in[8];
    float* Out = (float*)d_out;

    unsigned short* WqT = (unsigned short*)d_ws;      // 40 KB of weight tables only
    unsigned short* WkT = WqT + 4096;
    unsigned short* WvT = WqT + 8192;
    unsigned short* WoT = WqT + 12288;

    hipLaunchKernelGGL(prep_kernel, dim3(4), dim3(256), 0, stream,
                       Wq, Wk, Wv, Wo, WqT, WkT, WvT, WoT);
    hipLaunchKernelGGL(fused_kernel, dim3(512), dim3(512), 0, stream,
                       X, WqT, WkT, WvT, WoT, bq, bk, bv, bo, Out);
}